// Round 5
// baseline (8667.327 us; speedup 1.0000x reference)
//
#include <hip/hip_runtime.h>
#include <hip/hip_bf16.h>
#include <math.h>

#define B_ 64
#define T_ 104
#define FEAT_ 20
#define PEMB_ 64
#define COND_ 256
#define SUB_ 40
#define NBF_ 100
#define STEPS_ 400

typedef short short8 __attribute__((ext_vector_type(8)));
typedef float floatx4 __attribute__((ext_vector_type(4)));
typedef unsigned int uintx4 __attribute__((ext_vector_type(4)));

__device__ inline unsigned short f2bf(float x){
  unsigned int u = __float_as_uint(x);
  unsigned int r = (u + 0x7fffu + ((u >> 16) & 1u)) >> 16;
  return (unsigned short)r;
}
__device__ inline float fast_tanh(float x){
  float e = __expf(2.f*x);
  return 1.f - 2.f*__builtin_amdgcn_rcpf(e + 1.f);
}
__device__ inline float fast_sigm(float x){
  return __builtin_amdgcn_rcpf(1.f + __expf(-x));
}
__device__ inline floatx4 mfma16(short8 a, short8 b, floatx4 c){
  return __builtin_amdgcn_mfma_f32_16x16x32_bf16(a, b, c, 0, 0, 0);
}
// Slow path: cross-XCD transport via the coherence point (MALL).
__device__ inline unsigned long long ld_coh_u64(const unsigned long long* p){
  return __hip_atomic_load(p, __ATOMIC_RELAXED, __HIP_MEMORY_SCOPE_AGENT);
}
__device__ inline unsigned int ld_coh_u32(const unsigned int* p){
  return __hip_atomic_load(p, __ATOMIC_RELAXED, __HIP_MEMORY_SCOPE_AGENT);
}
__device__ inline void st_coh_u32(unsigned int* p, unsigned int v){
  __hip_atomic_store(p, v, __ATOMIC_RELAXED, __HIP_MEMORY_SCOPE_AGENT);
}
// Fast path: volatile store (write-through into the XCD's L2) and volatile
// load (L1-bypass -> served by the XCD's L2). No inline asm.
__device__ inline void st_fast_u32(unsigned int* p, unsigned int v){
  *(volatile unsigned int*)p = v;
}
__device__ inline unsigned long long ld_fast_u64(const unsigned long long* p){
  return *(const volatile unsigned long long*)p;
}

// ---------------------------------------------------------------------------
// Tagged-payload transfer. Each u32 = (step_tag16 << 16) | bf16 value.
// Per iteration: try the FAST snapshot (local L2); if any tag is stale, try
// the SLOW coherent snapshot (MALL) — identical to the proven round-1 poll —
// so progress is guaranteed regardless of XCD placement or volatile-load
// semantics. Fast slots are reader-zeroed at init, so a cross-XCD reader can
// never see a stale passing tag: its own L2 copy stays zero forever.
// ---------------------------------------------------------------------------
template<int STRIDE, int GCOFF>
__device__ inline void xfer(const unsigned int* __restrict__ fsrc,
                            const unsigned int* __restrict__ ssrc,
                            char* dst, unsigned tgt, int tid){
  int c0 = tid, c1 = tid + 256;
  int r0 = c0 >> 5, g0 = c0 & 31;
  int r1 = c1 >> 5, g1 = c1 & 31;
  const unsigned long long* f0 = (const unsigned long long*)fsrc + (r0*128 + g0*4);
  const unsigned long long* f1 = (const unsigned long long*)fsrc + (r1*128 + g1*4);
  const unsigned long long* s0 = (const unsigned long long*)ssrc + (r0*128 + g0*4);
  const unsigned long long* s1 = (const unsigned long long*)ssrc + (r1*128 + g1*4);
  unsigned long long w[8];
  for (;;){
    // fast snapshot (local L2)
    #pragma unroll
    for (int u = 0; u < 4; ++u) w[u]   = ld_fast_u64(f0 + u);
    #pragma unroll
    for (int u = 0; u < 4; ++u) w[4+u] = ld_fast_u64(f1 + u);
    unsigned mt = 0xFFFFu;
    #pragma unroll
    for (int u = 0; u < 8; ++u){
      mt = min(mt, (unsigned)(w[u] >> 16) & 0xFFFFu);
      mt = min(mt, (unsigned)(w[u] >> 48));
    }
    if (__all((int)(mt >= tgt))) break;
    // slow snapshot (coherent, MALL) — guaranteed progress
    #pragma unroll
    for (int u = 0; u < 4; ++u) w[u]   = ld_coh_u64(s0 + u);
    #pragma unroll
    for (int u = 0; u < 4; ++u) w[4+u] = ld_coh_u64(s1 + u);
    mt = 0xFFFFu;
    #pragma unroll
    for (int u = 0; u < 8; ++u){
      mt = min(mt, (unsigned)(w[u] >> 16) & 0xFFFFu);
      mt = min(mt, (unsigned)(w[u] >> 48));
    }
    if (__all((int)(mt >= tgt))) break;
    __builtin_amdgcn_s_sleep(1);
  }
  unsigned int pk0[4], pk1[4];
  #pragma unroll
  for (int u = 0; u < 4; ++u){
    pk0[u] = ((unsigned int)w[u]   & 0xFFFFu) | ((unsigned int)(w[u]   >> 32) << 16);
    pk1[u] = ((unsigned int)w[4+u] & 0xFFFFu) | ((unsigned int)(w[4+u] >> 32) << 16);
  }
  uintx4 v0 = {pk0[0], pk0[1], pk0[2], pk0[3]};
  uintx4 v1 = {pk1[0], pk1[1], pk1[2], pk1[3]};
  *(uintx4*)(dst + (size_t)(r0*STRIDE + ((GCOFF + g0) ^ (r0 & 7)))*16) = v0;
  *(uintx4*)(dst + (size_t)(r1*STRIDE + ((GCOFF + g1) ^ (r1 & 7)))*16) = v1;
}

// ---------------- phase embedding ----------------
__global__ void k_phase(const int* __restrict__ period, const float* __restrict__ rshift,
                        float* __restrict__ pr, float* __restrict__ pi){
  int b = blockIdx.x;
  __shared__ float cumf[NBF_], w0f[NBF_];
  if (threadIdx.x == 0){
    double acc = 2.0*M_PI*(double)rshift[b];
    for (int f = 0; f < NBF_; ++f){
      double w0 = 2.0*M_PI/(double)period[b*T_ + 3 + f];
      cumf[f] = (float)fmod(acc, 2.0*M_PI);
      w0f[f] = (float)w0;
      acc += 160.0*w0;
    }
  }
  __syncthreads();
  for (int e = threadIdx.x; e < NBF_*160; e += blockDim.x){
    int f = e/160, j = e - f*160;
    float ph = cumf[f] + w0f[f]*(float)j;
    int s = f*4 + j/40, u = j%40;
    pr[((size_t)b*STEPS_ + s)*SUB_ + u] = cosf(ph);
    pi[((size_t)b*STEPS_ + s)*SUB_ + u] = sinf(ph);
  }
}

// ---------------- prep ----------------
__global__ void k_prep(const float* __restrict__ c1w, const float* __restrict__ c2w,
                       float* __restrict__ w1t, float* __restrict__ w2t,
                       unsigned int* __restrict__ coh){
  size_t tid = (size_t)blockIdx.x*blockDim.x + threadIdx.x;
  size_t nt = (size_t)gridDim.x*blockDim.x;
  // zero slow tagged buffers + cnt (coherent zone)
  for (size_t e = tid; e < 131392; e += nt) st_coh_u32(coh + e, 0u);
  for (size_t e = tid; e < 768u*256u; e += nt){
    int kk = (int)(e >> 8), o = (int)(e & 255);
    int i = kk & 255, kc = kk >> 8;
    w1t[e] = c1w[(size_t)o*768 + i*3 + kc];
    w2t[e] = c2w[(size_t)o*768 + i*3 + kc];
  }
}

// ---------------- generic fp32 tiled GEMM (M x K x 256) ----------------
template<int MODE>
__global__ __launch_bounds__(256) void k_gemm(
    const float* __restrict__ a0, const float* __restrict__ a1, const float* __restrict__ a2,
    const int* __restrict__ ip,
    const float* __restrict__ Bm, const float* __restrict__ bias, float* __restrict__ C)
{
  constexpr int KT = (MODE==0) ? 6 : (MODE==1||MODE==2) ? 48 : (MODE==3) ? 16 : 21;
  __shared__ float As[16][68];
  __shared__ float Bs[16][68];
  int tid = threadIdx.x;
  int m0 = blockIdx.x*64, n0 = blockIdx.y*64;
  int tx = tid & 15, ty = tid >> 4;
  float acc[4][4] = {};
  int am = m0 + (tid >> 2);
  int akq = (tid & 3)*4;
  int bk = tid >> 4;
  int bn4 = (tid & 15)*4;

  for (int kt = 0; kt < KT; ++kt){
    int kbase = kt*16;
    float av[4];
    {
      int k0 = kbase + akq;
      if constexpr (MODE==0){
        if (k0 < 20){
          const float* p = a0 + (size_t)am*FEAT_ + k0;
          #pragma unroll
          for (int u=0;u<4;++u) av[u] = p[u];
        } else if (k0 < 84){
          const float* p = a1 + (size_t)ip[am]*PEMB_ + (k0-20);
          #pragma unroll
          for (int u=0;u<4;++u) av[u] = p[u];
        } else { av[0]=av[1]=av[2]=av[3]=0.f; }
      } else if constexpr (MODE==1){
        int b = am/102, t2 = am - b*102;
        int i = k0 & 255, kc = k0 >> 8;
        const float* p = a0 + ((size_t)(b*T_ + t2 + kc))*COND_ + i;
        #pragma unroll
        for (int u=0;u<4;++u) av[u] = p[u];
      } else if constexpr (MODE==2){
        int b = am/100, t2 = am - b*100;
        int i = k0 & 255, kc = k0 >> 8;
        const float* p = a0 + ((size_t)(b*102 + t2 + kc))*COND_ + i;
        #pragma unroll
        for (int u=0;u<4;++u) av[u] = p[u];
      } else if constexpr (MODE==3){
        const float* p = a0 + (size_t)am*COND_ + k0;
        #pragma unroll
        for (int u=0;u<4;++u) av[u] = p[u];
      } else {
        int b = am/400, s = am - b*400;
        const float* p;
        if (k0 < 256)      p = a0 + ((size_t)(b*100 + (s>>2)))*COND_ + k0;
        else if (k0 < 296) p = a1 + ((size_t)(b*400 + s))*SUB_ + (k0-256);
        else               p = a2 + ((size_t)(b*400 + s))*SUB_ + (k0-296);
        #pragma unroll
        for (int u=0;u<4;++u) av[u] = p[u];
      }
    }
    float bv[4];
    {
      int kB = kbase + bk;
      if constexpr (MODE==0){
        if (kB < 84){
          const float* p = Bm + (size_t)kB*256 + n0 + bn4;
          #pragma unroll
          for (int u=0;u<4;++u) bv[u] = p[u];
        } else { bv[0]=bv[1]=bv[2]=bv[3]=0.f; }
      } else if constexpr (MODE==4){
        int krow = (kB < 256) ? kB : kB + 40;
        const float* p = Bm + (size_t)krow*256 + n0 + bn4;
        #pragma unroll
        for (int u=0;u<4;++u) bv[u] = p[u];
      } else {
        const float* p = Bm + (size_t)kB*256 + n0 + bn4;
        #pragma unroll
        for (int u=0;u<4;++u) bv[u] = p[u];
      }
    }
    #pragma unroll
    for (int u=0;u<4;++u) As[akq+u][tid>>2] = av[u];
    #pragma unroll
    for (int u=0;u<4;++u) Bs[bk][bn4+u] = bv[u];
    __syncthreads();
    #pragma unroll
    for (int k = 0; k < 16; ++k){
      float a4[4], b4[4];
      #pragma unroll
      for (int i=0;i<4;++i) a4[i] = As[k][ty*4+i];
      #pragma unroll
      for (int j=0;j<4;++j) b4[j] = Bs[k][tx*4+j];
      #pragma unroll
      for (int i=0;i<4;++i)
        #pragma unroll
        for (int j=0;j<4;++j)
          acc[i][j] += a4[i]*b4[j];
    }
    __syncthreads();
  }
  #pragma unroll
  for (int i=0;i<4;++i){
    int m = m0 + ty*4 + i;
    #pragma unroll
    for (int j=0;j<4;++j){
      int n = n0 + tx*4 + j;
      float v = acc[i][j] + bias[n];
      if constexpr (MODE == 4){
        int b = m/400, s = m - b*400;
        C[((size_t)s*64 + b)*256 + n] = v;     // transposed [s][b][c]
      } else {
        C[(size_t)m*256 + n] = fast_tanh(v);
      }
    }
  }
}

// ---------------- persistent AR scan ----------------
// Grid 512; live blocks have (bI&7)<4, cluster g=bI&7 so a whole ring
// (S1+G1+G2+G3, 64 blocks) lands on one XCD under round-robin dispatch.
// Producers dual-store (volatile fast + coherent slow); consumers poll the
// fast snapshot first, coherent second. Reader-zeroed fast slots make any
// non-co-located placement degrade safely to the round-1 slow path.
__global__ __launch_bounds__(256, 1) void k_scan(
  const float* __restrict__ sd1_w, const float* __restrict__ sd2_w, const float* __restrict__ sd2_b,
  const float* __restrict__ g1_wi, const float* __restrict__ g1_bi, const float* __restrict__ g1_wh, const float* __restrict__ g1_bh,
  const float* __restrict__ g2_wi, const float* __restrict__ g2_bi, const float* __restrict__ g2_wh, const float* __restrict__ g2_bh,
  const float* __restrict__ g3_wi, const float* __restrict__ g3_bi, const float* __restrict__ g3_wh, const float* __restrict__ g3_bh,
  const float* __restrict__ out_w, const float* __restrict__ out_b,
  const float* __restrict__ tt1p,
  unsigned int* __restrict__ tt2buf, unsigned int* __restrict__ h1buf,
  unsigned int* __restrict__ h2buf, unsigned int* __restrict__ h3buf,
  unsigned int* __restrict__ tt2F, unsigned int* __restrict__ h1F,
  unsigned int* __restrict__ h2F, unsigned int* __restrict__ h3F,
  unsigned int* __restrict__ cnt,
  float* __restrict__ out)
{
  __shared__ __align__(16) char smem[65536];
  int bI = blockIdx.x;
  int cl = bI & 7;
  if (cl >= 4) return;              // dead block: frees its slot immediately
  int g = cl;
  int inner = bI >> 3;              // 0..63
  int set = inner >> 4, sl = inner & 15;
  int tid = threadIdx.x;
  int lane = tid & 63, wave = tid >> 6;
  int q = lane >> 4, nI = lane & 15;
  int b0 = g*16;

  // ---- reader-side zeroing of the fast slots this block will READ ----
  if (set == 0){
    for (int e = tid; e < 8192; e += 256){
      int p = e >> 12;
      st_fast_u32(h3F + ((size_t)p*4 + g)*4096 + (e & 4095), 0u);
    }
  } else {
    unsigned int* ownF = (set==1) ? h1F : (set==2) ? h2F : h3F;
    unsigned int* xF   = (set==1) ? tt2F : (set==2) ? h1F : h2F;
    for (int e = tid; e < 8192; e += 256){
      int p = e >> 12;
      st_fast_u32(ownF + ((size_t)p*4 + g)*4096 + (e & 4095), 0u);
      st_fast_u32(xF   + ((size_t)p*4 + g)*4096 + (e & 4095), 0u);
    }
  }
  __syncthreads();                  // drains zero-stores into L2
  if (tid == 0){
    __hip_atomic_fetch_add(cnt, 1u, __ATOMIC_RELAXED, __HIP_MEMORY_SCOPE_AGENT);
    while (ld_coh_u32(cnt) < 256u) __builtin_amdgcn_s_sleep(8);
  }
  __syncthreads();

  if (set == 0){
    // ===== S1: h3 -> prev -> tt1 -> tt2-slice =====
    char* outwF = smem;            // 24576
    char* sd1p0 = smem + 24576;    // 16384
    char* sd1p1 = smem + 40960;    // 4096
    char* sd2F  = smem + 45056;    // 8192
    char* stage = smem + 53248;    // 8192
    char* prevl = smem + 61440;    // 2304
    int col1 = sl*16 + nI;

    for (int t = wave; t < 24; t += 4){
      int nt = t >> 3, kk = t & 7;
      int c = nt*16 + nI;
      unsigned short v[8];
      #pragma unroll
      for (int j = 0; j < 8; ++j){
        int k = kk*32 + q*8 + j;
        v[j] = (c < 40) ? f2bf(out_w[(size_t)k*40 + c]) : (unsigned short)0;
      }
      *(short8*)(outwF + (t*64 + lane)*16) = *(short8*)v;
    }
    for (int t = wave; t < 16; t += 4){
      unsigned short v[8];
      #pragma unroll
      for (int j = 0; j < 8; ++j){
        int k = q*8 + j;
        v[j] = f2bf(sd1_w[(size_t)(256+k)*256 + t*16 + nI]);
      }
      *(short8*)(sd1p0 + (t*64 + lane)*16) = *(short8*)v;
    }
    {
      int nt = tid >> 4, ln = tid & 15;
      unsigned short v[8];
      #pragma unroll
      for (int j = 0; j < 8; ++j)
        v[j] = f2bf(sd1_w[(size_t)(256+32+j)*256 + nt*16 + ln]);
      *(short8*)(sd1p1 + tid*16) = *(short8*)v;
    }
    for (int t = wave; t < 8; t += 4){
      unsigned short v[8];
      #pragma unroll
      for (int j = 0; j < 8; ++j){
        int k = t*32 + q*8 + j;
        v[j] = f2bf(sd2_w[(size_t)k*256 + col1]);
      }
      *(short8*)(sd2F + (t*64 + lane)*16) = *(short8*)v;
    }
    for (int e = tid; e < 16*72; e += 256) *(unsigned short*)(prevl + e*2) = 0;
    float bout = 0.f;
    if (wave < 3){ int c = wave*16 + nI; if (c < 40) bout = out_b[c]; }
    float bsd2 = sd2_b[col1];
    __syncthreads();

    for (int s = 0; s <= STEPS_; ++s){
      float t1r[16];
      if (s < STEPS_){
        const float* tb = tt1p + ((size_t)s*64 + b0)*256;
        #pragma unroll
        for (int ii = 0; ii < 4; ++ii){
          int c = (wave*4 + ii)*16 + nI;
          #pragma unroll
          for (int i = 0; i < 4; ++i)
            t1r[ii*4+i] = tb[(q*4+i)*256 + c];
        }
      }
      if (s > 0){
        size_t pb = ((size_t)((s+1)&1)*4 + g)*4096;
        xfer<32,0>(h3F + pb, h3buf + pb, stage, (unsigned)s, tid);
        __syncthreads();
        if (wave < 3){
          floatx4 acc = {0.f,0.f,0.f,0.f};
          #pragma unroll
          for (int kk = 0; kk < 8; ++kk){
            short8 a = *(const short8*)(stage + (nI*32 + ((kk*4+q) ^ (nI & 7)))*16);
            short8 b = *(const short8*)(outwF + ((wave*8+kk)*64 + lane)*16);
            acc = mfma16(a, b, acc);
          }
          int c = wave*16 + nI;
          #pragma unroll
          for (int i = 0; i < 4; ++i){
            int row = q*4 + i;
            float pv = (c < 40) ? fast_tanh(acc[i] + bout) : 0.f;
            *(unsigned short*)(prevl + (row*72 + c)*2) = f2bf(pv);
            if (sl == 0 && c < 40)
              out[(size_t)(b0+row)*16000 + (size_t)(s-1)*40 + c] = pv;
          }
        }
      }
      if (s == STEPS_) break;
      __syncthreads();
      // tt1 = tanh(tt1p[s] + prev @ sd1p) -> stage
      #pragma unroll
      for (int ii = 0; ii < 4; ++ii){
        int nt = wave*4 + ii;
        floatx4 acc = {0.f,0.f,0.f,0.f};
        short8 a0v = *(const short8*)(prevl + nI*144 + q*16);
        short8 b0v = *(const short8*)(sd1p0 + (nt*64 + lane)*16);
        acc = mfma16(a0v, b0v, acc);
        short8 a1v = *(const short8*)(prevl + nI*144 + 64 + q*16);
        short8 b1v = {0,0,0,0,0,0,0,0};
        if (q == 0) b1v = *(const short8*)(sd1p1 + (nt*16 + nI)*16);
        acc = mfma16(a1v, b1v, acc);
        int c = nt*16 + nI;
        #pragma unroll
        for (int i = 0; i < 4; ++i){
          int row = q*4 + i;
          float tv = fast_tanh(acc[i] + t1r[ii*4+i]);
          int gc = c >> 3;
          *(unsigned short*)(stage + (row*32 + (gc ^ (row & 7)))*16 + (c & 7)*2) = f2bf(tv);
        }
      }
      __syncthreads();
      if (wave == 0){
        floatx4 acc = {0.f,0.f,0.f,0.f};
        #pragma unroll
        for (int kk = 0; kk < 8; ++kk){
          short8 a = *(const short8*)(stage + (nI*32 + ((kk*4+q) ^ (nI & 7)))*16);
          short8 b = *(const short8*)(sd2F + (kk*64 + lane)*16);
          acc = mfma16(a, b, acc);
        }
        size_t pb = ((size_t)(s&1)*4 + g)*4096;
        unsigned int* t2  = tt2buf + pb;
        unsigned int* t2f = tt2F + pb;
        unsigned tg = (unsigned)(s+1) << 16;
        #pragma unroll
        for (int i = 0; i < 4; ++i){
          int row = q*4 + i;
          unsigned pw = tg | (unsigned)f2bf(fast_tanh(acc[i] + bsd2));
          int idx = row*256 + col1;
          st_fast_u32(t2f + idx, pw);
          st_coh_u32(t2 + idx, pw);
        }
      }
      __syncthreads();
    }
  } else {
    // ===== GRU set =====
    int gi_ = set - 1;
    const float* wi = (gi_==0) ? g1_wi : (gi_==1) ? g2_wi : g3_wi;
    const float* wh = (gi_==0) ? g1_wh : (gi_==1) ? g2_wh : g3_wh;
    const float* bi = (gi_==0) ? g1_bi : (gi_==1) ? g2_bi : g3_bi;
    const float* bh = (gi_==0) ? g1_bh : (gi_==1) ? g2_bh : g3_bh;
    unsigned int* hOut  = (gi_==0) ? h1buf : (gi_==1) ? h2buf : h3buf;
    unsigned int* hOutF = (gi_==0) ? h1F : (gi_==1) ? h2F : h3F;
    const unsigned int* xBase  = (gi_==0) ? tt2buf : (gi_==1) ? h1buf : h2buf;
    const unsigned int* xBaseF = (gi_==0) ? tt2F : (gi_==1) ? h1F : h2F;
    char* wlds  = smem;          // 49152
    char* stage = smem + 49152;  // 16384: 16 rows x 64 chunks ([x | h])
    int hc0 = sl*16;

    for (int t = wave; t < 48; t += 4){
      unsigned short v[8];
      #pragma unroll
      for (int j = 0; j < 8; ++j){
        float w;
        if (t < 32){
          int k512 = (t & 15)*32 + q*8 + j;
          int col = ((t < 16) ? 0 : 256) + hc0 + nI;
          w = (k512 < 256) ? wi[(size_t)k512*768 + col] : wh[(size_t)(k512-256)*768 + col];
        } else if (t < 40){
          int k = (t-32)*32 + q*8 + j;
          w = wi[(size_t)k*768 + 512 + hc0 + nI];
        } else {
          int k = (t-40)*32 + q*8 + j;
          w = wh[(size_t)k*768 + 512 + hc0 + nI];
        }
        v[j] = f2bf(w);
      }
      *(short8*)(wlds + (t*64 + lane)*16) = *(short8*)v;
    }
    int erow = tid >> 4, ecol = tid & 15;
    int cg = hc0 + ecol;
    float br  = bi[cg] + bh[cg];
    float bz  = bi[256+cg] + bh[256+cg];
    float bin = bi[512+cg];
    float bhn = bh[512+cg];
    float hstate = 0.f;
    __syncthreads();

    for (int s = 0; s < STEPS_; ++s){
      // --- phase A: sibling h(s-1) exchange, h-half MFMAs ---
      {
        size_t pb = ((size_t)((s+1)&1)*4 + g)*4096;
        xfer<64,32>(hOutF + pb, hOut + pb, stage, (unsigned)s, tid);
      }
      __syncthreads();
      floatx4 acc = {0.f,0.f,0.f,0.f};
      if (wave < 2){
        int tb = wave*16;
        #pragma unroll
        for (int kt = 8; kt < 16; ++kt){
          short8 a = *(const short8*)(stage + (nI*64 + ((kt*4+q) ^ (nI & 7)))*16);
          short8 b = *(const short8*)(wlds + ((tb+kt)*64 + lane)*16);
          acc = mfma16(a, b, acc);
        }
      } else if (wave == 3){
        #pragma unroll
        for (int kt = 0; kt < 8; ++kt){
          short8 a = *(const short8*)(stage + (nI*64 + ((32 + kt*4+q) ^ (nI & 7)))*16);
          short8 b = *(const short8*)(wlds + ((40+kt)*64 + lane)*16);
          acc = mfma16(a, b, acc);
        }
      }
      // --- phase B: wait for x(s), stage it, x-half MFMAs ---
      {
        size_t pb = ((size_t)(s&1)*4 + g)*4096;
        xfer<64,0>(xBaseF + pb, xBase + pb, stage, (unsigned)(s+1), tid);
      }
      __syncthreads();
      if (wave < 2){
        int tb = wave*16;
        #pragma unroll
        for (int kt = 0; kt < 8; ++kt){
          short8 a = *(const short8*)(stage + (nI*64 + ((kt*4+q) ^ (nI & 7)))*16);
          short8 b = *(const short8*)(wlds + ((tb+kt)*64 + lane)*16);
          acc = mfma16(a, b, acc);
        }
      } else if (wave == 2){
        #pragma unroll
        for (int kt = 0; kt < 8; ++kt){
          short8 a = *(const short8*)(stage + (nI*64 + ((kt*4+q) ^ (nI & 7)))*16);
          short8 b = *(const short8*)(wlds + ((32+kt)*64 + lane)*16);
          acc = mfma16(a, b, acc);
        }
      }
      __syncthreads();
      float* ex = (float*)stage;
      {
        float* dst = ex + wave*256;
        #pragma unroll
        for (int i = 0; i < 4; ++i) dst[(q*4+i)*16 + nI] = acc[i];
      }
      __syncthreads();
      {
        float rv  = fast_sigm(ex[tid] + br);
        float zv  = fast_sigm(ex[256 + tid] + bz);
        float nv  = fast_tanh(ex[512 + tid] + bin + rv*(ex[768 + tid] + bhn));
        float hv  = (1.f - zv)*nv + zv*hstate;
        hstate = hv;
        size_t pb = ((size_t)(s&1)*4 + g)*4096;
        unsigned pw = ((unsigned)(s+1) << 16) | (unsigned)f2bf(hv);
        int idx = erow*256 + cg;
        st_fast_u32(hOutF + pb + idx, pw);
        st_coh_u32(hOut + pb + idx, pw);
        if (s == STEPS_-1)
          out[1024000 + gi_*16384 + (size_t)(b0+erow)*256 + cg] = hv;
      }
      __syncthreads();
    }
  }
}

extern "C" void kernel_launch(void* const* d_in, const int* in_sizes, int n_in,
                              void* d_out, int out_size, void* d_ws, size_t ws_size,
                              hipStream_t stream){
  (void)in_sizes; (void)n_in; (void)out_size; (void)ws_size;
  const float* features = (const float*)d_in[0];
  const int*   period   = (const int*)d_in[1];
  const float* rshift   = (const float*)d_in[3];
  const float* pembed   = (const float*)d_in[4];
  const float* fd1_w = (const float*)d_in[5];  const float* fd1_b = (const float*)d_in[6];
  const float* c1w   = (const float*)d_in[7];  const float* c1b   = (const float*)d_in[8];
  const float* c2w   = (const float*)d_in[9];  const float* c2b   = (const float*)d_in[10];
  const float* fd2_w = (const float*)d_in[11]; const float* fd2_b = (const float*)d_in[12];
  const float* sd1_w = (const float*)d_in[13]; const float* sd1_b = (const float*)d_in[14];
  const float* sd2_w = (const float*)d_in[15]; const float* sd2_b = (const float*)d_in[16];
  const float* g1_wi = (const float*)d_in[17]; const float* g1_bi = (const float*)d_in[18];
  const float* g1_wh = (const float*)d_in[19]; const float* g1_bh = (const float*)d_in[20];
  const float* g2_wi = (const float*)d_in[21]; const float* g2_bi = (const float*)d_in[22];
  const float* g2_wh = (const float*)d_in[23]; const float* g2_bh = (const float*)d_in[24];
  const float* g3_wi = (const float*)d_in[25]; const float* g3_bi = (const float*)d_in[26];
  const float* g3_wh = (const float*)d_in[27]; const float* g3_bh = (const float*)d_in[28];
  const float* out_w = (const float*)d_in[29]; const float* out_b = (const float*)d_in[30];

  char* ws = (char*)d_ws;
  size_t off = 0;
  auto alloc = [&](size_t bytes)->char*{
    char* p = ws + off; off += (bytes + 255) & ~(size_t)255; return p;
  };
  // coherent zone (zeroed by k_prep): 4 slow buffers + cnt
  unsigned int* coh = (unsigned int*)alloc(131392u*4u);
  unsigned int* tt2b = coh;
  unsigned int* h1b  = coh + 32768;
  unsigned int* h2b  = coh + 65536;
  unsigned int* h3b  = coh + 98304;
  unsigned int* cnt  = coh + 131072;
  // fast zone (reader-initialized inside k_scan; NOT touched by k_prep)
  unsigned int* fastz = (unsigned int*)alloc(131072u*4u);
  unsigned int* tt2F = fastz;
  unsigned int* h1F  = fastz + 32768;
  unsigned int* h2F  = fastz + 65536;
  unsigned int* h3F  = fastz + 98304;
  float* tt1p = (float*)alloc((size_t)B_*STEPS_*COND_*4);   // [s][b][c]
  float* pr   = (float*)alloc((size_t)B_*STEPS_*SUB_*4);
  float* pi   = (float*)alloc((size_t)B_*STEPS_*SUB_*4);
  float* tbuf = (float*)alloc((size_t)B_*T_*COND_*4);
  float* x1   = (float*)alloc((size_t)B_*102*COND_*4);
  float* x2   = (float*)alloc((size_t)B_*100*COND_*4);
  float* cb   = (float*)alloc((size_t)B_*100*COND_*4);
  float* w1t  = (float*)alloc((size_t)768*256*4);
  float* w2t  = (float*)alloc((size_t)768*256*4);

  k_phase<<<64, 256, 0, stream>>>(period, rshift, pr, pi);
  k_prep<<<256, 256, 0, stream>>>(c1w, c2w, w1t, w2t, coh);
  k_gemm<0><<<dim3(104,4), 256, 0, stream>>>(features, pembed, nullptr, period, fd1_w, fd1_b, tbuf);
  k_gemm<1><<<dim3(102,4), 256, 0, stream>>>(tbuf, nullptr, nullptr, nullptr, w1t, c1b, x1);
  k_gemm<2><<<dim3(100,4), 256, 0, stream>>>(x1, nullptr, nullptr, nullptr, w2t, c2b, x2);
  k_gemm<3><<<dim3(100,4), 256, 0, stream>>>(x2, nullptr, nullptr, nullptr, fd2_w, fd2_b, cb);
  k_gemm<4><<<dim3(400,4), 256, 0, stream>>>(cb, pr, pi, nullptr, sd1_w, sd1_b, tt1p);
  k_scan<<<512, 256, 0, stream>>>(sd1_w, sd2_w, sd2_b,
                                  g1_wi, g1_bi, g1_wh, g1_bh,
                                  g2_wi, g2_bi, g2_wh, g2_bh,
                                  g3_wi, g3_bi, g3_wh, g3_bh,
                                  out_w, out_b, tt1p,
                                  tt2b, h1b, h2b, h3b,
                                  tt2F, h1F, h2F, h3F,
                                  cnt, (float*)d_out);
}

// Round 6
// 6087.263 us; speedup vs baseline: 1.4238x; 1.4238x over previous
//
#include <hip/hip_runtime.h>
#include <hip/hip_bf16.h>
#include <math.h>

#define B_ 64
#define T_ 104
#define FEAT_ 20
#define PEMB_ 64
#define COND_ 256
#define SUB_ 40
#define NBF_ 100
#define STEPS_ 400

typedef short short8 __attribute__((ext_vector_type(8)));
typedef float floatx4 __attribute__((ext_vector_type(4)));
typedef unsigned int uintx4 __attribute__((ext_vector_type(4)));

__device__ inline unsigned short f2bf(float x){
  unsigned int u = __float_as_uint(x);
  unsigned int r = (u + 0x7fffu + ((u >> 16) & 1u)) >> 16;
  return (unsigned short)r;
}
__device__ inline float fast_tanh(float x){
  float e = __expf(2.f*x);
  return 1.f - 2.f*__builtin_amdgcn_rcpf(e + 1.f);
}
__device__ inline float fast_sigm(float x){
  return __builtin_amdgcn_rcpf(1.f + __expf(-x));
}
__device__ inline floatx4 mfma16(short8 a, short8 b, floatx4 c){
  return __builtin_amdgcn_mfma_f32_16x16x32_bf16(a, b, c, 0, 0, 0);
}
// Slow path: cross-XCD transport via the coherence point (MALL).
__device__ inline unsigned long long ld_coh_u64(const unsigned long long* p){
  return __hip_atomic_load(p, __ATOMIC_RELAXED, __HIP_MEMORY_SCOPE_AGENT);
}
__device__ inline void st_coh_u32(unsigned int* p, unsigned int v){
  __hip_atomic_store(p, v, __ATOMIC_RELAXED, __HIP_MEMORY_SCOPE_AGENT);
}
// Fast path producer: PLAIN store -> write-back, lands and stays in the
// producing XCD's L2 (round-5 lesson: volatile = sc0 sc1 = bypasses L2).
__device__ inline void st_fast_u32(unsigned int* p, unsigned int v){
  *p = v;
}

// ---------------------------------------------------------------------------
// Tagged-payload transfer. Each u32 = (step_tag16 << 16) | bf16 value.
// Poll loop: 4 FAST attempts (sc0 loads: L1-bypass, served by the local L2 —
// hits the producer's dirty line when co-located on the same XCD), then one
// SLOW coherent attempt (MALL; guaranteed progress for any placement), then
// sleep. Tags-in-data make any stale/foreign snapshot fail verification, so
// correctness never depends on block->XCD placement.
// ---------------------------------------------------------------------------
template<int STRIDE, int GCOFF>
__device__ inline void xfer(const unsigned int* __restrict__ fsrc,
                            const unsigned int* __restrict__ ssrc,
                            char* dst, unsigned tgt, int tid){
  int c0 = tid, c1 = tid + 256;
  int r0 = c0 >> 5, g0 = c0 & 31;
  int r1 = c1 >> 5, g1 = c1 & 31;
  const unsigned int* f0 = fsrc + (r0*256 + g0*8);
  const unsigned int* f1 = fsrc + (r1*256 + g1*8);
  const unsigned long long* s0 = (const unsigned long long*)ssrc + (r0*128 + g0*4);
  const unsigned long long* s1 = (const unsigned long long*)ssrc + (r1*128 + g1*4);
  unsigned long long w[8];
  bool got = false;
  for (;;){
    #pragma unroll 1
    for (int t = 0; t < 4 && !got; ++t){
      uintx4 a0, a1, b0, b1;
      asm volatile(
        "global_load_dwordx4 %0, %4, off sc0\n\t"
        "global_load_dwordx4 %1, %4, off offset:16 sc0\n\t"
        "global_load_dwordx4 %2, %5, off sc0\n\t"
        "global_load_dwordx4 %3, %5, off offset:16 sc0\n\t"
        "s_waitcnt vmcnt(0)"
        : "=&v"(a0), "=&v"(a1), "=&v"(b0), "=&v"(b1)
        : "v"(f0), "v"(f1) : "memory");
      unsigned mt = 0xFFFFu;
      #pragma unroll
      for (int u = 0; u < 4; ++u){
        mt = min(mt, a0[u] >> 16); mt = min(mt, a1[u] >> 16);
        mt = min(mt, b0[u] >> 16); mt = min(mt, b1[u] >> 16);
      }
      if (__all((int)(mt >= tgt))){
        w[0] = (unsigned long long)a0[0] | ((unsigned long long)a0[1] << 32);
        w[1] = (unsigned long long)a0[2] | ((unsigned long long)a0[3] << 32);
        w[2] = (unsigned long long)a1[0] | ((unsigned long long)a1[1] << 32);
        w[3] = (unsigned long long)a1[2] | ((unsigned long long)a1[3] << 32);
        w[4] = (unsigned long long)b0[0] | ((unsigned long long)b0[1] << 32);
        w[5] = (unsigned long long)b0[2] | ((unsigned long long)b0[3] << 32);
        w[6] = (unsigned long long)b1[0] | ((unsigned long long)b1[1] << 32);
        w[7] = (unsigned long long)b1[2] | ((unsigned long long)b1[3] << 32);
        got = true;
      }
    }
    if (got) break;
    // slow coherent snapshot (MALL) — guaranteed progress
    #pragma unroll
    for (int u = 0; u < 4; ++u) w[u]   = ld_coh_u64(s0 + u);
    #pragma unroll
    for (int u = 0; u < 4; ++u) w[4+u] = ld_coh_u64(s1 + u);
    unsigned mt = 0xFFFFu;
    #pragma unroll
    for (int u = 0; u < 8; ++u){
      mt = min(mt, (unsigned)(w[u] >> 16) & 0xFFFFu);
      mt = min(mt, (unsigned)(w[u] >> 48));
    }
    if (__all((int)(mt >= tgt))) break;
    __builtin_amdgcn_s_sleep(1);
  }
  unsigned int pk0[4], pk1[4];
  #pragma unroll
  for (int u = 0; u < 4; ++u){
    pk0[u] = ((unsigned int)w[u]   & 0xFFFFu) | ((unsigned int)(w[u]   >> 32) << 16);
    pk1[u] = ((unsigned int)w[4+u] & 0xFFFFu) | ((unsigned int)(w[4+u] >> 32) << 16);
  }
  uintx4 v0 = {pk0[0], pk0[1], pk0[2], pk0[3]};
  uintx4 v1 = {pk1[0], pk1[1], pk1[2], pk1[3]};
  *(uintx4*)(dst + (size_t)(r0*STRIDE + ((GCOFF + g0) ^ (r0 & 7)))*16) = v0;
  *(uintx4*)(dst + (size_t)(r1*STRIDE + ((GCOFF + g1) ^ (r1 & 7)))*16) = v1;
}

// ---------------- phase embedding ----------------
__global__ void k_phase(const int* __restrict__ period, const float* __restrict__ rshift,
                        float* __restrict__ pr, float* __restrict__ pi){
  int b = blockIdx.x;
  __shared__ float cumf[NBF_], w0f[NBF_];
  if (threadIdx.x == 0){
    double acc = 2.0*M_PI*(double)rshift[b];
    for (int f = 0; f < NBF_; ++f){
      double w0 = 2.0*M_PI/(double)period[b*T_ + 3 + f];
      cumf[f] = (float)fmod(acc, 2.0*M_PI);
      w0f[f] = (float)w0;
      acc += 160.0*w0;
    }
  }
  __syncthreads();
  for (int e = threadIdx.x; e < NBF_*160; e += blockDim.x){
    int f = e/160, j = e - f*160;
    float ph = cumf[f] + w0f[f]*(float)j;
    int s = f*4 + j/40, u = j%40;
    pr[((size_t)b*STEPS_ + s)*SUB_ + u] = cosf(ph);
    pi[((size_t)b*STEPS_ + s)*SUB_ + u] = sinf(ph);
  }
}

// ---------------- prep ----------------
__global__ void k_prep(const float* __restrict__ c1w, const float* __restrict__ c2w,
                       float* __restrict__ w1t, float* __restrict__ w2t,
                       unsigned int* __restrict__ coh){
  size_t tid = (size_t)blockIdx.x*blockDim.x + threadIdx.x;
  size_t nt = (size_t)gridDim.x*blockDim.x;
  // zero slow tagged buffers + fast zone (both coherently -> zeros visible
  // at MALL so a cold/foreign fast read can never see a passing tag)
  for (size_t e = tid; e < 262464; e += nt) st_coh_u32(coh + e, 0u);
  for (size_t e = tid; e < 768u*256u; e += nt){
    int kk = (int)(e >> 8), o = (int)(e & 255);
    int i = kk & 255, kc = kk >> 8;
    w1t[e] = c1w[(size_t)o*768 + i*3 + kc];
    w2t[e] = c2w[(size_t)o*768 + i*3 + kc];
  }
}

// ---------------- generic fp32 tiled GEMM (M x K x 256) ----------------
template<int MODE>
__global__ __launch_bounds__(256) void k_gemm(
    const float* __restrict__ a0, const float* __restrict__ a1, const float* __restrict__ a2,
    const int* __restrict__ ip,
    const float* __restrict__ Bm, const float* __restrict__ bias, float* __restrict__ C)
{
  constexpr int KT = (MODE==0) ? 6 : (MODE==1||MODE==2) ? 48 : (MODE==3) ? 16 : 21;
  __shared__ float As[16][68];
  __shared__ float Bs[16][68];
  int tid = threadIdx.x;
  int m0 = blockIdx.x*64, n0 = blockIdx.y*64;
  int tx = tid & 15, ty = tid >> 4;
  float acc[4][4] = {};
  int am = m0 + (tid >> 2);
  int akq = (tid & 3)*4;
  int bk = tid >> 4;
  int bn4 = (tid & 15)*4;

  for (int kt = 0; kt < KT; ++kt){
    int kbase = kt*16;
    float av[4];
    {
      int k0 = kbase + akq;
      if constexpr (MODE==0){
        if (k0 < 20){
          const float* p = a0 + (size_t)am*FEAT_ + k0;
          #pragma unroll
          for (int u=0;u<4;++u) av[u] = p[u];
        } else if (k0 < 84){
          const float* p = a1 + (size_t)ip[am]*PEMB_ + (k0-20);
          #pragma unroll
          for (int u=0;u<4;++u) av[u] = p[u];
        } else { av[0]=av[1]=av[2]=av[3]=0.f; }
      } else if constexpr (MODE==1){
        int b = am/102, t2 = am - b*102;
        int i = k0 & 255, kc = k0 >> 8;
        const float* p = a0 + ((size_t)(b*T_ + t2 + kc))*COND_ + i;
        #pragma unroll
        for (int u=0;u<4;++u) av[u] = p[u];
      } else if constexpr (MODE==2){
        int b = am/100, t2 = am - b*100;
        int i = k0 & 255, kc = k0 >> 8;
        const float* p = a0 + ((size_t)(b*102 + t2 + kc))*COND_ + i;
        #pragma unroll
        for (int u=0;u<4;++u) av[u] = p[u];
      } else if constexpr (MODE==3){
        const float* p = a0 + (size_t)am*COND_ + k0;
        #pragma unroll
        for (int u=0;u<4;++u) av[u] = p[u];
      } else {
        int b = am/400, s = am - b*400;
        const float* p;
        if (k0 < 256)      p = a0 + ((size_t)(b*100 + (s>>2)))*COND_ + k0;
        else if (k0 < 296) p = a1 + ((size_t)(b*400 + s))*SUB_ + (k0-256);
        else               p = a2 + ((size_t)(b*400 + s))*SUB_ + (k0-296);
        #pragma unroll
        for (int u=0;u<4;++u) av[u] = p[u];
      }
    }
    float bv[4];
    {
      int kB = kbase + bk;
      if constexpr (MODE==0){
        if (kB < 84){
          const float* p = Bm + (size_t)kB*256 + n0 + bn4;
          #pragma unroll
          for (int u=0;u<4;++u) bv[u] = p[u];
        } else { bv[0]=bv[1]=bv[2]=bv[3]=0.f; }
      } else if constexpr (MODE==4){
        int krow = (kB < 256) ? kB : kB + 40;
        const float* p = Bm + (size_t)krow*256 + n0 + bn4;
        #pragma unroll
        for (int u=0;u<4;++u) bv[u] = p[u];
      } else {
        const float* p = Bm + (size_t)kB*256 + n0 + bn4;
        #pragma unroll
        for (int u=0;u<4;++u) bv[u] = p[u];
      }
    }
    #pragma unroll
    for (int u=0;u<4;++u) As[akq+u][tid>>2] = av[u];
    #pragma unroll
    for (int u=0;u<4;++u) Bs[bk][bn4+u] = bv[u];
    __syncthreads();
    #pragma unroll
    for (int k = 0; k < 16; ++k){
      float a4[4], b4[4];
      #pragma unroll
      for (int i=0;i<4;++i) a4[i] = As[k][ty*4+i];
      #pragma unroll
      for (int j=0;j<4;++j) b4[j] = Bs[k][tx*4+j];
      #pragma unroll
      for (int i=0;i<4;++i)
        #pragma unroll
        for (int j=0;j<4;++j)
          acc[i][j] += a4[i]*b4[j];
    }
    __syncthreads();
  }
  #pragma unroll
  for (int i=0;i<4;++i){
    int m = m0 + ty*4 + i;
    #pragma unroll
    for (int j=0;j<4;++j){
      int n = n0 + tx*4 + j;
      float v = acc[i][j] + bias[n];
      if constexpr (MODE == 4){
        int b = m/400, s = m - b*400;
        C[((size_t)s*64 + b)*256 + n] = v;     // transposed [s][b][c]
      } else {
        C[(size_t)m*256 + n] = fast_tanh(v);
      }
    }
  }
}

// ---------------- persistent AR scan ----------------
// Grid 512; live blocks have (bI&7)<4, cluster g=bI&7 so a whole ring
// (S1+G1+G2+G3, 64 blocks) lands on one XCD under round-robin dispatch.
// Producers dual-store (plain->local L2 + coherent->MALL); consumers poll
// fast (sc0/L2) with coherent fallback. Tags-in-data keep every placement
// correct; co-location only changes speed.
__global__ __launch_bounds__(256, 1) void k_scan(
  const float* __restrict__ sd1_w, const float* __restrict__ sd2_w, const float* __restrict__ sd2_b,
  const float* __restrict__ g1_wi, const float* __restrict__ g1_bi, const float* __restrict__ g1_wh, const float* __restrict__ g1_bh,
  const float* __restrict__ g2_wi, const float* __restrict__ g2_bi, const float* __restrict__ g2_wh, const float* __restrict__ g2_bh,
  const float* __restrict__ g3_wi, const float* __restrict__ g3_bi, const float* __restrict__ g3_wh, const float* __restrict__ g3_bh,
  const float* __restrict__ out_w, const float* __restrict__ out_b,
  const float* __restrict__ tt1p,
  unsigned int* __restrict__ tt2buf, unsigned int* __restrict__ h1buf,
  unsigned int* __restrict__ h2buf, unsigned int* __restrict__ h3buf,
  unsigned int* __restrict__ tt2F, unsigned int* __restrict__ h1F,
  unsigned int* __restrict__ h2F, unsigned int* __restrict__ h3F,
  float* __restrict__ out)
{
  __shared__ __align__(16) char smem[65536];
  int bI = blockIdx.x;
  int cl = bI & 7;
  if (cl >= 4) return;              // dead block: frees its slot immediately
  int g = cl;
  int inner = bI >> 3;              // 0..63
  int set = inner >> 4, sl = inner & 15;
  int tid = threadIdx.x;
  int lane = tid & 63, wave = tid >> 6;
  int q = lane >> 4, nI = lane & 15;
  int b0 = g*16;

  if (set == 0){
    // ===== S1: h3 -> prev -> tt1 -> tt2-slice =====
    char* outwF = smem;            // 24576
    char* sd1p0 = smem + 24576;    // 16384
    char* sd1p1 = smem + 40960;    // 4096
    char* sd2F  = smem + 45056;    // 8192
    char* stage = smem + 53248;    // 8192
    char* prevl = smem + 61440;    // 2304
    int col1 = sl*16 + nI;

    for (int t = wave; t < 24; t += 4){
      int nt = t >> 3, kk = t & 7;
      int c = nt*16 + nI;
      unsigned short v[8];
      #pragma unroll
      for (int j = 0; j < 8; ++j){
        int k = kk*32 + q*8 + j;
        v[j] = (c < 40) ? f2bf(out_w[(size_t)k*40 + c]) : (unsigned short)0;
      }
      *(short8*)(outwF + (t*64 + lane)*16) = *(short8*)v;
    }
    for (int t = wave; t < 16; t += 4){
      unsigned short v[8];
      #pragma unroll
      for (int j = 0; j < 8; ++j){
        int k = q*8 + j;
        v[j] = f2bf(sd1_w[(size_t)(256+k)*256 + t*16 + nI]);
      }
      *(short8*)(sd1p0 + (t*64 + lane)*16) = *(short8*)v;
    }
    {
      int nt = tid >> 4, ln = tid & 15;
      unsigned short v[8];
      #pragma unroll
      for (int j = 0; j < 8; ++j)
        v[j] = f2bf(sd1_w[(size_t)(256+32+j)*256 + nt*16 + ln]);
      *(short8*)(sd1p1 + tid*16) = *(short8*)v;
    }
    for (int t = wave; t < 8; t += 4){
      unsigned short v[8];
      #pragma unroll
      for (int j = 0; j < 8; ++j){
        int k = t*32 + q*8 + j;
        v[j] = f2bf(sd2_w[(size_t)k*256 + col1]);
      }
      *(short8*)(sd2F + (t*64 + lane)*16) = *(short8*)v;
    }
    for (int e = tid; e < 16*72; e += 256) *(unsigned short*)(prevl + e*2) = 0;
    float bout = 0.f;
    if (wave < 3){ int c = wave*16 + nI; if (c < 40) bout = out_b[c]; }
    float bsd2 = sd2_b[col1];
    __syncthreads();

    for (int s = 0; s <= STEPS_; ++s){
      float t1r[16];
      if (s < STEPS_){
        const float* tb = tt1p + ((size_t)s*64 + b0)*256;
        #pragma unroll
        for (int ii = 0; ii < 4; ++ii){
          int c = (wave*4 + ii)*16 + nI;
          #pragma unroll
          for (int i = 0; i < 4; ++i)
            t1r[ii*4+i] = tb[(q*4+i)*256 + c];
        }
      }
      if (s > 0){
        size_t pb = ((size_t)((s+1)&1)*4 + g)*4096;
        xfer<32,0>(h3F + pb, h3buf + pb, stage, (unsigned)s, tid);
        __syncthreads();
        if (wave < 3){
          floatx4 acc = {0.f,0.f,0.f,0.f};
          #pragma unroll
          for (int kk = 0; kk < 8; ++kk){
            short8 a = *(const short8*)(stage + (nI*32 + ((kk*4+q) ^ (nI & 7)))*16);
            short8 b = *(const short8*)(outwF + ((wave*8+kk)*64 + lane)*16);
            acc = mfma16(a, b, acc);
          }
          int c = wave*16 + nI;
          #pragma unroll
          for (int i = 0; i < 4; ++i){
            int row = q*4 + i;
            float pv = (c < 40) ? fast_tanh(acc[i] + bout) : 0.f;
            *(unsigned short*)(prevl + (row*72 + c)*2) = f2bf(pv);
            if (sl == 0 && c < 40)
              out[(size_t)(b0+row)*16000 + (size_t)(s-1)*40 + c] = pv;
          }
        }
      }
      if (s == STEPS_) break;
      __syncthreads();
      // tt1 = tanh(tt1p[s] + prev @ sd1p) -> stage
      #pragma unroll
      for (int ii = 0; ii < 4; ++ii){
        int nt = wave*4 + ii;
        floatx4 acc = {0.f,0.f,0.f,0.f};
        short8 a0v = *(const short8*)(prevl + nI*144 + q*16);
        short8 b0v = *(const short8*)(sd1p0 + (nt*64 + lane)*16);
        acc = mfma16(a0v, b0v, acc);
        short8 a1v = *(const short8*)(prevl + nI*144 + 64 + q*16);
        short8 b1v = {0,0,0,0,0,0,0,0};
        if (q == 0) b1v = *(const short8*)(sd1p1 + (nt*16 + nI)*16);
        acc = mfma16(a1v, b1v, acc);
        int c = nt*16 + nI;
        #pragma unroll
        for (int i = 0; i < 4; ++i){
          int row = q*4 + i;
          float tv = fast_tanh(acc[i] + t1r[ii*4+i]);
          int gc = c >> 3;
          *(unsigned short*)(stage + (row*32 + (gc ^ (row & 7)))*16 + (c & 7)*2) = f2bf(tv);
        }
      }
      __syncthreads();
      if (wave == 0){
        floatx4 acc = {0.f,0.f,0.f,0.f};
        #pragma unroll
        for (int kk = 0; kk < 8; ++kk){
          short8 a = *(const short8*)(stage + (nI*32 + ((kk*4+q) ^ (nI & 7)))*16);
          short8 b = *(const short8*)(sd2F + (kk*64 + lane)*16);
          acc = mfma16(a, b, acc);
        }
        size_t pb = ((size_t)(s&1)*4 + g)*4096;
        unsigned int* t2  = tt2buf + pb;
        unsigned int* t2f = tt2F + pb;
        unsigned tg = (unsigned)(s+1) << 16;
        #pragma unroll
        for (int i = 0; i < 4; ++i){
          int row = q*4 + i;
          unsigned pw = tg | (unsigned)f2bf(fast_tanh(acc[i] + bsd2));
          int idx = row*256 + col1;
          st_fast_u32(t2f + idx, pw);
          st_coh_u32(t2 + idx, pw);
        }
      }
      __syncthreads();
    }
  } else {
    // ===== GRU set =====
    int gi_ = set - 1;
    const float* wi = (gi_==0) ? g1_wi : (gi_==1) ? g2_wi : g3_wi;
    const float* wh = (gi_==0) ? g1_wh : (gi_==1) ? g2_wh : g3_wh;
    const float* bi = (gi_==0) ? g1_bi : (gi_==1) ? g2_bi : g3_bi;
    const float* bh = (gi_==0) ? g1_bh : (gi_==1) ? g2_bh : g3_bh;
    unsigned int* hOut  = (gi_==0) ? h1buf : (gi_==1) ? h2buf : h3buf;
    unsigned int* hOutF = (gi_==0) ? h1F : (gi_==1) ? h2F : h3F;
    const unsigned int* xBase  = (gi_==0) ? tt2buf : (gi_==1) ? h1buf : h2buf;
    const unsigned int* xBaseF = (gi_==0) ? tt2F : (gi_==1) ? h1F : h2F;
    char* wlds  = smem;          // 49152
    char* stage = smem + 49152;  // 16384: 16 rows x 64 chunks ([x | h])
    int hc0 = sl*16;

    for (int t = wave; t < 48; t += 4){
      unsigned short v[8];
      #pragma unroll
      for (int j = 0; j < 8; ++j){
        float w;
        if (t < 32){
          int k512 = (t & 15)*32 + q*8 + j;
          int col = ((t < 16) ? 0 : 256) + hc0 + nI;
          w = (k512 < 256) ? wi[(size_t)k512*768 + col] : wh[(size_t)(k512-256)*768 + col];
        } else if (t < 40){
          int k = (t-32)*32 + q*8 + j;
          w = wi[(size_t)k*768 + 512 + hc0 + nI];
        } else {
          int k = (t-40)*32 + q*8 + j;
          w = wh[(size_t)k*768 + 512 + hc0 + nI];
        }
        v[j] = f2bf(w);
      }
      *(short8*)(wlds + (t*64 + lane)*16) = *(short8*)v;
    }
    int erow = tid >> 4, ecol = tid & 15;
    int cg = hc0 + ecol;
    float br  = bi[cg] + bh[cg];
    float bz  = bi[256+cg] + bh[256+cg];
    float bin = bi[512+cg];
    float bhn = bh[512+cg];
    float hstate = 0.f;
    __syncthreads();

    for (int s = 0; s < STEPS_; ++s){
      // --- phase A: sibling h(s-1) exchange, h-half MFMAs ---
      {
        size_t pb = ((size_t)((s+1)&1)*4 + g)*4096;
        xfer<64,32>(hOutF + pb, hOut + pb, stage, (unsigned)s, tid);
      }
      __syncthreads();
      floatx4 acc = {0.f,0.f,0.f,0.f};
      if (wave < 2){
        int tb = wave*16;
        #pragma unroll
        for (int kt = 8; kt < 16; ++kt){
          short8 a = *(const short8*)(stage + (nI*64 + ((kt*4+q) ^ (nI & 7)))*16);
          short8 b = *(const short8*)(wlds + ((tb+kt)*64 + lane)*16);
          acc = mfma16(a, b, acc);
        }
      } else if (wave == 3){
        #pragma unroll
        for (int kt = 0; kt < 8; ++kt){
          short8 a = *(const short8*)(stage + (nI*64 + ((32 + kt*4+q) ^ (nI & 7)))*16);
          short8 b = *(const short8*)(wlds + ((40+kt)*64 + lane)*16);
          acc = mfma16(a, b, acc);
        }
      }
      // --- phase B: wait for x(s), stage it, x-half MFMAs ---
      {
        size_t pb = ((size_t)(s&1)*4 + g)*4096;
        xfer<64,0>(xBaseF + pb, xBase + pb, stage, (unsigned)(s+1), tid);
      }
      __syncthreads();
      if (wave < 2){
        int tb = wave*16;
        #pragma unroll
        for (int kt = 0; kt < 8; ++kt){
          short8 a = *(const short8*)(stage + (nI*64 + ((kt*4+q) ^ (nI & 7)))*16);
          short8 b = *(const short8*)(wlds + ((tb+kt)*64 + lane)*16);
          acc = mfma16(a, b, acc);
        }
      } else if (wave == 2){
        #pragma unroll
        for (int kt = 0; kt < 8; ++kt){
          short8 a = *(const short8*)(stage + (nI*64 + ((kt*4+q) ^ (nI & 7)))*16);
          short8 b = *(const short8*)(wlds + ((32+kt)*64 + lane)*16);
          acc = mfma16(a, b, acc);
        }
      }
      __syncthreads();
      float* ex = (float*)stage;
      {
        float* dst = ex + wave*256;
        #pragma unroll
        for (int i = 0; i < 4; ++i) dst[(q*4+i)*16 + nI] = acc[i];
      }
      __syncthreads();
      {
        float rv  = fast_sigm(ex[tid] + br);
        float zv  = fast_sigm(ex[256 + tid] + bz);
        float nv  = fast_tanh(ex[512 + tid] + bin + rv*(ex[768 + tid] + bhn));
        float hv  = (1.f - zv)*nv + zv*hstate;
        hstate = hv;
        size_t pb = ((size_t)(s&1)*4 + g)*4096;
        unsigned pw = ((unsigned)(s+1) << 16) | (unsigned)f2bf(hv);
        int idx = erow*256 + cg;
        st_fast_u32(hOutF + pb + idx, pw);
        st_coh_u32(hOut + pb + idx, pw);
        if (s == STEPS_-1)
          out[1024000 + gi_*16384 + (size_t)(b0+erow)*256 + cg] = hv;
      }
      __syncthreads();
    }
  }
}

extern "C" void kernel_launch(void* const* d_in, const int* in_sizes, int n_in,
                              void* d_out, int out_size, void* d_ws, size_t ws_size,
                              hipStream_t stream){
  (void)in_sizes; (void)n_in; (void)out_size; (void)ws_size;
  const float* features = (const float*)d_in[0];
  const int*   period   = (const int*)d_in[1];
  const float* rshift   = (const float*)d_in[3];
  const float* pembed   = (const float*)d_in[4];
  const float* fd1_w = (const float*)d_in[5];  const float* fd1_b = (const float*)d_in[6];
  const float* c1w   = (const float*)d_in[7];  const float* c1b   = (const float*)d_in[8];
  const float* c2w   = (const float*)d_in[9];  const float* c2b   = (const float*)d_in[10];
  const float* fd2_w = (const float*)d_in[11]; const float* fd2_b = (const float*)d_in[12];
  const float* sd1_w = (const float*)d_in[13]; const float* sd1_b = (const float*)d_in[14];
  const float* sd2_w = (const float*)d_in[15]; const float* sd2_b = (const float*)d_in[16];
  const float* g1_wi = (const float*)d_in[17]; const float* g1_bi = (const float*)d_in[18];
  const float* g1_wh = (const float*)d_in[19]; const float* g1_bh = (const float*)d_in[20];
  const float* g2_wi = (const float*)d_in[21]; const float* g2_bi = (const float*)d_in[22];
  const float* g2_wh = (const float*)d_in[23]; const float* g2_bh = (const float*)d_in[24];
  const float* g3_wi = (const float*)d_in[25]; const float* g3_bi = (const float*)d_in[26];
  const float* g3_wh = (const float*)d_in[27]; const float* g3_bh = (const float*)d_in[28];
  const float* out_w = (const float*)d_in[29]; const float* out_b = (const float*)d_in[30];

  char* ws = (char*)d_ws;
  size_t off = 0;
  auto alloc = [&](size_t bytes)->char*{
    char* p = ws + off; off += (bytes + 255) & ~(size_t)255; return p;
  };
  // coherent slow zone + fast zone, contiguous (both zeroed by k_prep)
  unsigned int* coh = (unsigned int*)alloc(131392u*4u);
  unsigned int* tt2b = coh;
  unsigned int* h1b  = coh + 32768;
  unsigned int* h2b  = coh + 65536;
  unsigned int* h3b  = coh + 98304;
  unsigned int* fastz = (unsigned int*)alloc(131072u*4u);  // == coh + 131392
  unsigned int* tt2F = fastz;
  unsigned int* h1F  = fastz + 32768;
  unsigned int* h2F  = fastz + 65536;
  unsigned int* h3F  = fastz + 98304;
  float* tt1p = (float*)alloc((size_t)B_*STEPS_*COND_*4);   // [s][b][c]
  float* pr   = (float*)alloc((size_t)B_*STEPS_*SUB_*4);
  float* pi   = (float*)alloc((size_t)B_*STEPS_*SUB_*4);
  float* tbuf = (float*)alloc((size_t)B_*T_*COND_*4);
  float* x1   = (float*)alloc((size_t)B_*102*COND_*4);
  float* x2   = (float*)alloc((size_t)B_*100*COND_*4);
  float* cb   = (float*)alloc((size_t)B_*100*COND_*4);
  float* w1t  = (float*)alloc((size_t)768*256*4);
  float* w2t  = (float*)alloc((size_t)768*256*4);

  k_phase<<<64, 256, 0, stream>>>(period, rshift, pr, pi);
  k_prep<<<256, 256, 0, stream>>>(c1w, c2w, w1t, w2t, coh);
  k_gemm<0><<<dim3(104,4), 256, 0, stream>>>(features, pembed, nullptr, period, fd1_w, fd1_b, tbuf);
  k_gemm<1><<<dim3(102,4), 256, 0, stream>>>(tbuf, nullptr, nullptr, nullptr, w1t, c1b, x1);
  k_gemm<2><<<dim3(100,4), 256, 0, stream>>>(x1, nullptr, nullptr, nullptr, w2t, c2b, x2);
  k_gemm<3><<<dim3(100,4), 256, 0, stream>>>(x2, nullptr, nullptr, nullptr, fd2_w, fd2_b, cb);
  k_gemm<4><<<dim3(400,4), 256, 0, stream>>>(cb, pr, pi, nullptr, sd1_w, sd1_b, tt1p);
  k_scan<<<512, 256, 0, stream>>>(sd1_w, sd2_w, sd2_b,
                                  g1_wi, g1_bi, g1_wh, g1_bh,
                                  g2_wi, g2_bi, g2_wh, g2_bh,
                                  g3_wi, g3_bi, g3_wh, g3_bh,
                                  out_w, out_b, tt1p,
                                  tt2b, h1b, h2b, h3b,
                                  tt2F, h1F, h2F, h3F,
                                  (float*)d_out);
}

// Round 7
// 5612.140 us; speedup vs baseline: 1.5444x; 1.0847x over previous
//
#include <hip/hip_runtime.h>
#include <hip/hip_bf16.h>
#include <math.h>

#define B_ 64
#define T_ 104
#define FEAT_ 20
#define PEMB_ 64
#define COND_ 256
#define SUB_ 40
#define NBF_ 100
#define STEPS_ 400

typedef short short8 __attribute__((ext_vector_type(8)));
typedef float floatx4 __attribute__((ext_vector_type(4)));
typedef unsigned int uintx4 __attribute__((ext_vector_type(4)));

__device__ inline unsigned short f2bf(float x){
  unsigned int u = __float_as_uint(x);
  unsigned int r = (u + 0x7fffu + ((u >> 16) & 1u)) >> 16;
  return (unsigned short)r;
}
__device__ inline float fast_tanh(float x){
  float e = __expf(2.f*x);
  return 1.f - 2.f*__builtin_amdgcn_rcpf(e + 1.f);
}
__device__ inline float fast_sigm(float x){
  return __builtin_amdgcn_rcpf(1.f + __expf(-x));
}
__device__ inline floatx4 mfma16(short8 a, short8 b, floatx4 c){
  return __builtin_amdgcn_mfma_f32_16x16x32_bf16(a, b, c, 0, 0, 0);
}
// Slow path: cross-XCD transport via the coherence point (MALL).
__device__ inline unsigned long long ld_coh_u64(const unsigned long long* p){
  return __hip_atomic_load(p, __ATOMIC_RELAXED, __HIP_MEMORY_SCOPE_AGENT);
}
__device__ inline void st_coh_u32(unsigned int* p, unsigned int v){
  __hip_atomic_store(p, v, __ATOMIC_RELAXED, __HIP_MEMORY_SCOPE_AGENT);
}
// Fast path producer: PLAIN store -> write-back, lands and stays in the
// producing XCD's L2 (round-5 lesson: volatile = sc0 sc1 = bypasses L2).
__device__ inline void st_fast_u32(unsigned int* p, unsigned int v){
  *p = v;
}

// ---------------------------------------------------------------------------
// Tagged-payload transfer. Each u32 = (step_tag16 << 16) | bf16 value.
// Spin body = ONE fast attempt (sc0 loads: L1-bypass, served by the local L2
// -> ~300cy granularity when the producer shares this XCD). A coherent slow
// attempt runs on the first miss and every 4th iteration thereafter (MALL;
// guaranteed progress for any placement). Tags-in-data make stale/foreign
// snapshots fail verification, so correctness never depends on placement.
// ---------------------------------------------------------------------------
template<int STRIDE, int GCOFF>
__device__ inline void xfer(const unsigned int* __restrict__ fsrc,
                            const unsigned int* __restrict__ ssrc,
                            char* dst, unsigned tgt, int tid){
  int c0 = tid, c1 = tid + 256;
  int r0 = c0 >> 5, g0 = c0 & 31;
  int r1 = c1 >> 5, g1 = c1 & 31;
  const unsigned int* f0 = fsrc + (r0*256 + g0*8);
  const unsigned int* f1 = fsrc + (r1*256 + g1*8);
  const unsigned long long* s0 = (const unsigned long long*)ssrc + (r0*128 + g0*4);
  const unsigned long long* s1 = (const unsigned long long*)ssrc + (r1*128 + g1*4);
  unsigned long long w[8];
  int it = 0;
  for (;;){
    // fast attempt (local L2 via sc0)
    uintx4 a0, a1, b0, b1;
    asm volatile(
      "global_load_dwordx4 %0, %4, off sc0\n\t"
      "global_load_dwordx4 %1, %4, off offset:16 sc0\n\t"
      "global_load_dwordx4 %2, %5, off sc0\n\t"
      "global_load_dwordx4 %3, %5, off offset:16 sc0\n\t"
      "s_waitcnt vmcnt(0)"
      : "=&v"(a0), "=&v"(a1), "=&v"(b0), "=&v"(b1)
      : "v"(f0), "v"(f1) : "memory");
    unsigned mt = 0xFFFFu;
    #pragma unroll
    for (int u = 0; u < 4; ++u){
      mt = min(mt, a0[u] >> 16); mt = min(mt, a1[u] >> 16);
      mt = min(mt, b0[u] >> 16); mt = min(mt, b1[u] >> 16);
    }
    if (__all((int)(mt >= tgt))){
      w[0] = (unsigned long long)a0[0] | ((unsigned long long)a0[1] << 32);
      w[1] = (unsigned long long)a0[2] | ((unsigned long long)a0[3] << 32);
      w[2] = (unsigned long long)a1[0] | ((unsigned long long)a1[1] << 32);
      w[3] = (unsigned long long)a1[2] | ((unsigned long long)a1[3] << 32);
      w[4] = (unsigned long long)b0[0] | ((unsigned long long)b0[1] << 32);
      w[5] = (unsigned long long)b0[2] | ((unsigned long long)b0[3] << 32);
      w[6] = (unsigned long long)b1[0] | ((unsigned long long)b1[1] << 32);
      w[7] = (unsigned long long)b1[2] | ((unsigned long long)b1[3] << 32);
      break;
    }
    if ((it++ & 3) == 0){
      // slow coherent snapshot (MALL) — guaranteed progress
      #pragma unroll
      for (int u = 0; u < 4; ++u) w[u]   = ld_coh_u64(s0 + u);
      #pragma unroll
      for (int u = 0; u < 4; ++u) w[4+u] = ld_coh_u64(s1 + u);
      mt = 0xFFFFu;
      #pragma unroll
      for (int u = 0; u < 8; ++u){
        mt = min(mt, (unsigned)(w[u] >> 16) & 0xFFFFu);
        mt = min(mt, (unsigned)(w[u] >> 48));
      }
      if (__all((int)(mt >= tgt))) break;
      __builtin_amdgcn_s_sleep(1);
    }
  }
  unsigned int pk0[4], pk1[4];
  #pragma unroll
  for (int u = 0; u < 4; ++u){
    pk0[u] = ((unsigned int)w[u]   & 0xFFFFu) | ((unsigned int)(w[u]   >> 32) << 16);
    pk1[u] = ((unsigned int)w[4+u] & 0xFFFFu) | ((unsigned int)(w[4+u] >> 32) << 16);
  }
  uintx4 v0 = {pk0[0], pk0[1], pk0[2], pk0[3]};
  uintx4 v1 = {pk1[0], pk1[1], pk1[2], pk1[3]};
  *(uintx4*)(dst + (size_t)(r0*STRIDE + ((GCOFF + g0) ^ (r0 & 7)))*16) = v0;
  *(uintx4*)(dst + (size_t)(r1*STRIDE + ((GCOFF + g1) ^ (r1 & 7)))*16) = v1;
}

// ---------------- phase embedding ----------------
__global__ void k_phase(const int* __restrict__ period, const float* __restrict__ rshift,
                        float* __restrict__ pr, float* __restrict__ pi){
  int b = blockIdx.x;
  __shared__ float cumf[NBF_], w0f[NBF_];
  if (threadIdx.x == 0){
    double acc = 2.0*M_PI*(double)rshift[b];
    for (int f = 0; f < NBF_; ++f){
      double w0 = 2.0*M_PI/(double)period[b*T_ + 3 + f];
      cumf[f] = (float)fmod(acc, 2.0*M_PI);
      w0f[f] = (float)w0;
      acc += 160.0*w0;
    }
  }
  __syncthreads();
  for (int e = threadIdx.x; e < NBF_*160; e += blockDim.x){
    int f = e/160, j = e - f*160;
    float ph = cumf[f] + w0f[f]*(float)j;
    int s = f*4 + j/40, u = j%40;
    pr[((size_t)b*STEPS_ + s)*SUB_ + u] = cosf(ph);
    pi[((size_t)b*STEPS_ + s)*SUB_ + u] = sinf(ph);
  }
}

// ---------------- prep ----------------
__global__ void k_prep(const float* __restrict__ c1w, const float* __restrict__ c2w,
                       float* __restrict__ w1t, float* __restrict__ w2t,
                       unsigned int* __restrict__ coh){
  size_t tid = (size_t)blockIdx.x*blockDim.x + threadIdx.x;
  size_t nt = (size_t)gridDim.x*blockDim.x;
  // zero slow tagged buffers + fast zone (both coherently -> zeros visible
  // at MALL so a cold/foreign fast read can never see a passing tag)
  for (size_t e = tid; e < 262464; e += nt) st_coh_u32(coh + e, 0u);
  for (size_t e = tid; e < 768u*256u; e += nt){
    int kk = (int)(e >> 8), o = (int)(e & 255);
    int i = kk & 255, kc = kk >> 8;
    w1t[e] = c1w[(size_t)o*768 + i*3 + kc];
    w2t[e] = c2w[(size_t)o*768 + i*3 + kc];
  }
}

// ---------------- generic fp32 tiled GEMM (M x K x 256) ----------------
template<int MODE>
__global__ __launch_bounds__(256) void k_gemm(
    const float* __restrict__ a0, const float* __restrict__ a1, const float* __restrict__ a2,
    const int* __restrict__ ip,
    const float* __restrict__ Bm, const float* __restrict__ bias, float* __restrict__ C)
{
  constexpr int KT = (MODE==0) ? 6 : (MODE==1||MODE==2) ? 48 : (MODE==3) ? 16 : 21;
  __shared__ float As[16][68];
  __shared__ float Bs[16][68];
  int tid = threadIdx.x;
  int m0 = blockIdx.x*64, n0 = blockIdx.y*64;
  int tx = tid & 15, ty = tid >> 4;
  float acc[4][4] = {};
  int am = m0 + (tid >> 2);
  int akq = (tid & 3)*4;
  int bk = tid >> 4;
  int bn4 = (tid & 15)*4;

  for (int kt = 0; kt < KT; ++kt){
    int kbase = kt*16;
    float av[4];
    {
      int k0 = kbase + akq;
      if constexpr (MODE==0){
        if (k0 < 20){
          const float* p = a0 + (size_t)am*FEAT_ + k0;
          #pragma unroll
          for (int u=0;u<4;++u) av[u] = p[u];
        } else if (k0 < 84){
          const float* p = a1 + (size_t)ip[am]*PEMB_ + (k0-20);
          #pragma unroll
          for (int u=0;u<4;++u) av[u] = p[u];
        } else { av[0]=av[1]=av[2]=av[3]=0.f; }
      } else if constexpr (MODE==1){
        int b = am/102, t2 = am - b*102;
        int i = k0 & 255, kc = k0 >> 8;
        const float* p = a0 + ((size_t)(b*T_ + t2 + kc))*COND_ + i;
        #pragma unroll
        for (int u=0;u<4;++u) av[u] = p[u];
      } else if constexpr (MODE==2){
        int b = am/100, t2 = am - b*100;
        int i = k0 & 255, kc = k0 >> 8;
        const float* p = a0 + ((size_t)(b*102 + t2 + kc))*COND_ + i;
        #pragma unroll
        for (int u=0;u<4;++u) av[u] = p[u];
      } else if constexpr (MODE==3){
        const float* p = a0 + (size_t)am*COND_ + k0;
        #pragma unroll
        for (int u=0;u<4;++u) av[u] = p[u];
      } else {
        int b = am/400, s = am - b*400;
        const float* p;
        if (k0 < 256)      p = a0 + ((size_t)(b*100 + (s>>2)))*COND_ + k0;
        else if (k0 < 296) p = a1 + ((size_t)(b*400 + s))*SUB_ + (k0-256);
        else               p = a2 + ((size_t)(b*400 + s))*SUB_ + (k0-296);
        #pragma unroll
        for (int u=0;u<4;++u) av[u] = p[u];
      }
    }
    float bv[4];
    {
      int kB = kbase + bk;
      if constexpr (MODE==0){
        if (kB < 84){
          const float* p = Bm + (size_t)kB*256 + n0 + bn4;
          #pragma unroll
          for (int u=0;u<4;++u) bv[u] = p[u];
        } else { bv[0]=bv[1]=bv[2]=bv[3]=0.f; }
      } else if constexpr (MODE==4){
        int krow = (kB < 256) ? kB : kB + 40;
        const float* p = Bm + (size_t)krow*256 + n0 + bn4;
        #pragma unroll
        for (int u=0;u<4;++u) bv[u] = p[u];
      } else {
        const float* p = Bm + (size_t)kB*256 + n0 + bn4;
        #pragma unroll
        for (int u=0;u<4;++u) bv[u] = p[u];
      }
    }
    #pragma unroll
    for (int u=0;u<4;++u) As[akq+u][tid>>2] = av[u];
    #pragma unroll
    for (int u=0;u<4;++u) Bs[bk][bn4+u] = bv[u];
    __syncthreads();
    #pragma unroll
    for (int k = 0; k < 16; ++k){
      float a4[4], b4[4];
      #pragma unroll
      for (int i=0;i<4;++i) a4[i] = As[k][ty*4+i];
      #pragma unroll
      for (int j=0;j<4;++j) b4[j] = Bs[k][tx*4+j];
      #pragma unroll
      for (int i=0;i<4;++i)
        #pragma unroll
        for (int j=0;j<4;++j)
          acc[i][j] += a4[i]*b4[j];
    }
    __syncthreads();
  }
  #pragma unroll
  for (int i=0;i<4;++i){
    int m = m0 + ty*4 + i;
    #pragma unroll
    for (int j=0;j<4;++j){
      int n = n0 + tx*4 + j;
      float v = acc[i][j] + bias[n];
      if constexpr (MODE == 4){
        int b = m/400, s = m - b*400;
        C[((size_t)s*64 + b)*256 + n] = v;     // transposed [s][b][c]
      } else {
        C[(size_t)m*256 + n] = fast_tanh(v);
      }
    }
  }
}

// ---------------- persistent AR scan ----------------
// Grid 512; live blocks have (bI&7)<4, cluster g=bI&7 so a whole ring
// (S1+G1+G2+G3, 64 blocks) lands on one XCD under round-robin dispatch.
// Producers dual-store (plain->local L2 + coherent->MALL); consumers spin on
// the fast sc0 probe with periodic coherent fallback. Tags-in-data keep
// every placement correct; co-location only changes speed.
__global__ __launch_bounds__(256, 1) void k_scan(
  const float* __restrict__ sd1_w, const float* __restrict__ sd2_w, const float* __restrict__ sd2_b,
  const float* __restrict__ g1_wi, const float* __restrict__ g1_bi, const float* __restrict__ g1_wh, const float* __restrict__ g1_bh,
  const float* __restrict__ g2_wi, const float* __restrict__ g2_bi, const float* __restrict__ g2_wh, const float* __restrict__ g2_bh,
  const float* __restrict__ g3_wi, const float* __restrict__ g3_bi, const float* __restrict__ g3_wh, const float* __restrict__ g3_bh,
  const float* __restrict__ out_w, const float* __restrict__ out_b,
  const float* __restrict__ tt1p,
  unsigned int* __restrict__ tt2buf, unsigned int* __restrict__ h1buf,
  unsigned int* __restrict__ h2buf, unsigned int* __restrict__ h3buf,
  unsigned int* __restrict__ tt2F, unsigned int* __restrict__ h1F,
  unsigned int* __restrict__ h2F, unsigned int* __restrict__ h3F,
  float* __restrict__ out)
{
  __shared__ __align__(16) char smem[65536];
  int bI = blockIdx.x;
  int cl = bI & 7;
  if (cl >= 4) return;              // dead block: frees its slot immediately
  int g = cl;
  int inner = bI >> 3;              // 0..63
  int set = inner >> 4, sl = inner & 15;
  int tid = threadIdx.x;
  int lane = tid & 63, wave = tid >> 6;
  int q = lane >> 4, nI = lane & 15;
  int b0 = g*16;

  if (set == 0){
    // ===== S1: h3 -> prev -> tt1 -> tt2-slice =====
    char* outwF = smem;            // 24576
    char* sd1p0 = smem + 24576;    // 16384
    char* sd1p1 = smem + 40960;    // 4096
    char* sd2F  = smem + 45056;    // 8192
    char* stage = smem + 53248;    // 8192
    char* prevl = smem + 61440;    // 2304
    int col1 = sl*16 + nI;

    for (int t = wave; t < 24; t += 4){
      int nt = t >> 3, kk = t & 7;
      int c = nt*16 + nI;
      unsigned short v[8];
      #pragma unroll
      for (int j = 0; j < 8; ++j){
        int k = kk*32 + q*8 + j;
        v[j] = (c < 40) ? f2bf(out_w[(size_t)k*40 + c]) : (unsigned short)0;
      }
      *(short8*)(outwF + (t*64 + lane)*16) = *(short8*)v;
    }
    for (int t = wave; t < 16; t += 4){
      unsigned short v[8];
      #pragma unroll
      for (int j = 0; j < 8; ++j){
        int k = q*8 + j;
        v[j] = f2bf(sd1_w[(size_t)(256+k)*256 + t*16 + nI]);
      }
      *(short8*)(sd1p0 + (t*64 + lane)*16) = *(short8*)v;
    }
    {
      int nt = tid >> 4, ln = tid & 15;
      unsigned short v[8];
      #pragma unroll
      for (int j = 0; j < 8; ++j)
        v[j] = f2bf(sd1_w[(size_t)(256+32+j)*256 + nt*16 + ln]);
      *(short8*)(sd1p1 + tid*16) = *(short8*)v;
    }
    for (int t = wave; t < 8; t += 4){
      unsigned short v[8];
      #pragma unroll
      for (int j = 0; j < 8; ++j){
        int k = t*32 + q*8 + j;
        v[j] = f2bf(sd2_w[(size_t)k*256 + col1]);
      }
      *(short8*)(sd2F + (t*64 + lane)*16) = *(short8*)v;
    }
    for (int e = tid; e < 16*72; e += 256) *(unsigned short*)(prevl + e*2) = 0;
    float bout = 0.f;
    if (wave < 3){ int c = wave*16 + nI; if (c < 40) bout = out_b[c]; }
    float bsd2 = sd2_b[col1];
    __syncthreads();

    for (int s = 0; s <= STEPS_; ++s){
      float t1r[16];
      if (s < STEPS_){
        const float* tb = tt1p + ((size_t)s*64 + b0)*256;
        #pragma unroll
        for (int ii = 0; ii < 4; ++ii){
          int c = (wave*4 + ii)*16 + nI;
          #pragma unroll
          for (int i = 0; i < 4; ++i)
            t1r[ii*4+i] = tb[(q*4+i)*256 + c];
        }
      }
      if (s > 0){
        size_t pb = ((size_t)((s+1)&1)*4 + g)*4096;
        xfer<32,0>(h3F + pb, h3buf + pb, stage, (unsigned)s, tid);
        __syncthreads();
        if (wave < 3){
          floatx4 acc = {0.f,0.f,0.f,0.f};
          #pragma unroll
          for (int kk = 0; kk < 8; ++kk){
            short8 a = *(const short8*)(stage + (nI*32 + ((kk*4+q) ^ (nI & 7)))*16);
            short8 b = *(const short8*)(outwF + ((wave*8+kk)*64 + lane)*16);
            acc = mfma16(a, b, acc);
          }
          int c = wave*16 + nI;
          #pragma unroll
          for (int i = 0; i < 4; ++i){
            int row = q*4 + i;
            float pv = (c < 40) ? fast_tanh(acc[i] + bout) : 0.f;
            *(unsigned short*)(prevl + (row*72 + c)*2) = f2bf(pv);
            if (sl == 0 && c < 40)
              out[(size_t)(b0+row)*16000 + (size_t)(s-1)*40 + c] = pv;
          }
        }
      }
      if (s == STEPS_) break;
      __syncthreads();
      // tt1 = tanh(tt1p[s] + prev @ sd1p) -> stage
      #pragma unroll
      for (int ii = 0; ii < 4; ++ii){
        int nt = wave*4 + ii;
        floatx4 acc = {0.f,0.f,0.f,0.f};
        short8 a0v = *(const short8*)(prevl + nI*144 + q*16);
        short8 b0v = *(const short8*)(sd1p0 + (nt*64 + lane)*16);
        acc = mfma16(a0v, b0v, acc);
        short8 a1v = *(const short8*)(prevl + nI*144 + 64 + q*16);
        short8 b1v = {0,0,0,0,0,0,0,0};
        if (q == 0) b1v = *(const short8*)(sd1p1 + (nt*16 + nI)*16);
        acc = mfma16(a1v, b1v, acc);
        int c = nt*16 + nI;
        #pragma unroll
        for (int i = 0; i < 4; ++i){
          int row = q*4 + i;
          float tv = fast_tanh(acc[i] + t1r[ii*4+i]);
          int gc = c >> 3;
          *(unsigned short*)(stage + (row*32 + (gc ^ (row & 7)))*16 + (c & 7)*2) = f2bf(tv);
        }
      }
      __syncthreads();
      if (wave == 0){
        floatx4 acc = {0.f,0.f,0.f,0.f};
        #pragma unroll
        for (int kk = 0; kk < 8; ++kk){
          short8 a = *(const short8*)(stage + (nI*32 + ((kk*4+q) ^ (nI & 7)))*16);
          short8 b = *(const short8*)(sd2F + (kk*64 + lane)*16);
          acc = mfma16(a, b, acc);
        }
        size_t pb = ((size_t)(s&1)*4 + g)*4096;
        unsigned int* t2  = tt2buf + pb;
        unsigned int* t2f = tt2F + pb;
        unsigned tg = (unsigned)(s+1) << 16;
        #pragma unroll
        for (int i = 0; i < 4; ++i){
          int row = q*4 + i;
          unsigned pw = tg | (unsigned)f2bf(fast_tanh(acc[i] + bsd2));
          int idx = row*256 + col1;
          st_fast_u32(t2f + idx, pw);
          st_coh_u32(t2 + idx, pw);
        }
      }
      __syncthreads();
    }
  } else {
    // ===== GRU set =====
    int gi_ = set - 1;
    const float* wi = (gi_==0) ? g1_wi : (gi_==1) ? g2_wi : g3_wi;
    const float* wh = (gi_==0) ? g1_wh : (gi_==1) ? g2_wh : g3_wh;
    const float* bi = (gi_==0) ? g1_bi : (gi_==1) ? g2_bi : g3_bi;
    const float* bh = (gi_==0) ? g1_bh : (gi_==1) ? g2_bh : g3_bh;
    unsigned int* hOut  = (gi_==0) ? h1buf : (gi_==1) ? h2buf : h3buf;
    unsigned int* hOutF = (gi_==0) ? h1F : (gi_==1) ? h2F : h3F;
    const unsigned int* xBase  = (gi_==0) ? tt2buf : (gi_==1) ? h1buf : h2buf;
    const unsigned int* xBaseF = (gi_==0) ? tt2F : (gi_==1) ? h1F : h2F;
    char* wlds  = smem;          // 49152
    char* stage = smem + 49152;  // 16384: 16 rows x 64 chunks ([x | h])
    int hc0 = sl*16;

    for (int t = wave; t < 48; t += 4){
      unsigned short v[8];
      #pragma unroll
      for (int j = 0; j < 8; ++j){
        float w;
        if (t < 32){
          int k512 = (t & 15)*32 + q*8 + j;
          int col = ((t < 16) ? 0 : 256) + hc0 + nI;
          w = (k512 < 256) ? wi[(size_t)k512*768 + col] : wh[(size_t)(k512-256)*768 + col];
        } else if (t < 40){
          int k = (t-32)*32 + q*8 + j;
          w = wi[(size_t)k*768 + 512 + hc0 + nI];
        } else {
          int k = (t-40)*32 + q*8 + j;
          w = wh[(size_t)k*768 + 512 + hc0 + nI];
        }
        v[j] = f2bf(w);
      }
      *(short8*)(wlds + (t*64 + lane)*16) = *(short8*)v;
    }
    int erow = tid >> 4, ecol = tid & 15;
    int cg = hc0 + ecol;
    float br  = bi[cg] + bh[cg];
    float bz  = bi[256+cg] + bh[256+cg];
    float bin = bi[512+cg];
    float bhn = bh[512+cg];
    float hstate = 0.f;
    __syncthreads();

    for (int s = 0; s < STEPS_; ++s){
      // --- phase A: sibling h(s-1) exchange, h-half MFMAs ---
      {
        size_t pb = ((size_t)((s+1)&1)*4 + g)*4096;
        xfer<64,32>(hOutF + pb, hOut + pb, stage, (unsigned)s, tid);
      }
      __syncthreads();
      floatx4 acc = {0.f,0.f,0.f,0.f};
      if (wave < 2){
        int tb = wave*16;
        #pragma unroll
        for (int kt = 8; kt < 16; ++kt){
          short8 a = *(const short8*)(stage + (nI*64 + ((kt*4+q) ^ (nI & 7)))*16);
          short8 b = *(const short8*)(wlds + ((tb+kt)*64 + lane)*16);
          acc = mfma16(a, b, acc);
        }
      } else if (wave == 3){
        #pragma unroll
        for (int kt = 0; kt < 8; ++kt){
          short8 a = *(const short8*)(stage + (nI*64 + ((32 + kt*4+q) ^ (nI & 7)))*16);
          short8 b = *(const short8*)(wlds + ((40+kt)*64 + lane)*16);
          acc = mfma16(a, b, acc);
        }
      }
      // --- phase B: wait for x(s), stage it, x-half MFMAs ---
      {
        size_t pb = ((size_t)(s&1)*4 + g)*4096;
        xfer<64,0>(xBaseF + pb, xBase + pb, stage, (unsigned)(s+1), tid);
      }
      __syncthreads();
      if (wave < 2){
        int tb = wave*16;
        #pragma unroll
        for (int kt = 0; kt < 8; ++kt){
          short8 a = *(const short8*)(stage + (nI*64 + ((kt*4+q) ^ (nI & 7)))*16);
          short8 b = *(const short8*)(wlds + ((tb+kt)*64 + lane)*16);
          acc = mfma16(a, b, acc);
        }
      } else if (wave == 2){
        #pragma unroll
        for (int kt = 0; kt < 8; ++kt){
          short8 a = *(const short8*)(stage + (nI*64 + ((kt*4+q) ^ (nI & 7)))*16);
          short8 b = *(const short8*)(wlds + ((32+kt)*64 + lane)*16);
          acc = mfma16(a, b, acc);
        }
      }
      __syncthreads();
      float* ex = (float*)stage;
      {
        float* dst = ex + wave*256;
        #pragma unroll
        for (int i = 0; i < 4; ++i) dst[(q*4+i)*16 + nI] = acc[i];
      }
      __syncthreads();
      {
        float rv  = fast_sigm(ex[tid] + br);
        float zv  = fast_sigm(ex[256 + tid] + bz);
        float nv  = fast_tanh(ex[512 + tid] + bin + rv*(ex[768 + tid] + bhn));
        float hv  = (1.f - zv)*nv + zv*hstate;
        hstate = hv;
        size_t pb = ((size_t)(s&1)*4 + g)*4096;
        unsigned pw = ((unsigned)(s+1) << 16) | (unsigned)f2bf(hv);
        int idx = erow*256 + cg;
        st_fast_u32(hOutF + pb + idx, pw);
        st_coh_u32(hOut + pb + idx, pw);
        if (s == STEPS_-1)
          out[1024000 + gi_*16384 + (size_t)(b0+erow)*256 + cg] = hv;
      }
      __syncthreads();
    }
  }
}

extern "C" void kernel_launch(void* const* d_in, const int* in_sizes, int n_in,
                              void* d_out, int out_size, void* d_ws, size_t ws_size,
                              hipStream_t stream){
  (void)in_sizes; (void)n_in; (void)out_size; (void)ws_size;
  const float* features = (const float*)d_in[0];
  const int*   period   = (const int*)d_in[1];
  const float* rshift   = (const float*)d_in[3];
  const float* pembed   = (const float*)d_in[4];
  const float* fd1_w = (const float*)d_in[5];  const float* fd1_b = (const float*)d_in[6];
  const float* c1w   = (const float*)d_in[7];  const float* c1b   = (const float*)d_in[8];
  const float* c2w   = (const float*)d_in[9];  const float* c2b   = (const float*)d_in[10];
  const float* fd2_w = (const float*)d_in[11]; const float* fd2_b = (const float*)d_in[12];
  const float* sd1_w = (const float*)d_in[13]; const float* sd1_b = (const float*)d_in[14];
  const float* sd2_w = (const float*)d_in[15]; const float* sd2_b = (const float*)d_in[16];
  const float* g1_wi = (const float*)d_in[17]; const float* g1_bi = (const float*)d_in[18];
  const float* g1_wh = (const float*)d_in[19]; const float* g1_bh = (const float*)d_in[20];
  const float* g2_wi = (const float*)d_in[21]; const float* g2_bi = (const float*)d_in[22];
  const float* g2_wh = (const float*)d_in[23]; const float* g2_bh = (const float*)d_in[24];
  const float* g3_wi = (const float*)d_in[25]; const float* g3_bi = (const float*)d_in[26];
  const float* g3_wh = (const float*)d_in[27]; const float* g3_bh = (const float*)d_in[28];
  const float* out_w = (const float*)d_in[29]; const float* out_b = (const float*)d_in[30];

  char* ws = (char*)d_ws;
  size_t off = 0;
  auto alloc = [&](size_t bytes)->char*{
    char* p = ws + off; off += (bytes + 255) & ~(size_t)255; return p;
  };
  // coherent slow zone + fast zone, contiguous (both zeroed by k_prep)
  unsigned int* coh = (unsigned int*)alloc(131392u*4u);
  unsigned int* tt2b = coh;
  unsigned int* h1b  = coh + 32768;
  unsigned int* h2b  = coh + 65536;
  unsigned int* h3b  = coh + 98304;
  unsigned int* fastz = (unsigned int*)alloc(131072u*4u);  // == coh + 131392
  unsigned int* tt2F = fastz;
  unsigned int* h1F  = fastz + 32768;
  unsigned int* h2F  = fastz + 65536;
  unsigned int* h3F  = fastz + 98304;
  float* tt1p = (float*)alloc((size_t)B_*STEPS_*COND_*4);   // [s][b][c]
  float* pr   = (float*)alloc((size_t)B_*STEPS_*SUB_*4);
  float* pi   = (float*)alloc((size_t)B_*STEPS_*SUB_*4);
  float* tbuf = (float*)alloc((size_t)B_*T_*COND_*4);
  float* x1   = (float*)alloc((size_t)B_*102*COND_*4);
  float* x2   = (float*)alloc((size_t)B_*100*COND_*4);
  float* cb   = (float*)alloc((size_t)B_*100*COND_*4);
  float* w1t  = (float*)alloc((size_t)768*256*4);
  float* w2t  = (float*)alloc((size_t)768*256*4);

  k_phase<<<64, 256, 0, stream>>>(period, rshift, pr, pi);
  k_prep<<<256, 256, 0, stream>>>(c1w, c2w, w1t, w2t, coh);
  k_gemm<0><<<dim3(104,4), 256, 0, stream>>>(features, pembed, nullptr, period, fd1_w, fd1_b, tbuf);
  k_gemm<1><<<dim3(102,4), 256, 0, stream>>>(tbuf, nullptr, nullptr, nullptr, w1t, c1b, x1);
  k_gemm<2><<<dim3(100,4), 256, 0, stream>>>(x1, nullptr, nullptr, nullptr, w2t, c2b, x2);
  k_gemm<3><<<dim3(100,4), 256, 0, stream>>>(x2, nullptr, nullptr, nullptr, fd2_w, fd2_b, cb);
  k_gemm<4><<<dim3(400,4), 256, 0, stream>>>(cb, pr, pi, nullptr, sd1_w, sd1_b, tt1p);
  k_scan<<<512, 256, 0, stream>>>(sd1_w, sd2_w, sd2_b,
                                  g1_wi, g1_bi, g1_wh, g1_bh,
                                  g2_wi, g2_bi, g2_wh, g2_bh,
                                  g3_wi, g3_bi, g3_wh, g3_bh,
                                  out_w, out_b, tt1p,
                                  tt2b, h1b, h2b, h3b,
                                  tt2F, h1F, h2F, h3F,
                                  (float*)d_out);
}